// Round 3
// baseline (1651.630 us; speedup 1.0000x reference)
//
#include <hip/hip_runtime.h>
#include <hip/hip_bf16.h>

typedef __hip_bfloat16 bf16;
typedef __attribute__((ext_vector_type(8))) short short8;
typedef __attribute__((ext_vector_type(4))) float float4v;

#define BK 32

__device__ __forceinline__ void gload16(const bf16* g, bf16* s) {
    __builtin_amdgcn_global_load_lds(
        (const __attribute__((address_space(1))) void*)g,
        (__attribute__((address_space(3))) void*)s, 16, 0, 0);
}

// ---------------- small utility kernels ----------------

__global__ void k_convert_x(const float* __restrict__ in, bf16* __restrict__ out,
                            int n, int* __restrict__ cnt) {
    if (blockIdx.x == 0 && threadIdx.x < 16) cnt[threadIdx.x] = 0;
    int i = (blockIdx.x * blockDim.x + threadIdx.x) * 4;
    if (i + 3 < n) {
        float4 v = *(const float4*)(in + i);
        out[i + 0] = __float2bfloat16(v.x);
        out[i + 1] = __float2bfloat16(v.y);
        out[i + 2] = __float2bfloat16(v.z);
        out[i + 3] = __float2bfloat16(v.w);
    }
}

// in: [R,S] fp32 -> out: [S,R] bf16 (batched over z). 256 threads, 32x32 tile.
// Read float4, write 4xbf16 (8B) per thread.
__global__ void k_transpose(const float* __restrict__ in, bf16* __restrict__ out,
                            int R, int S) {
    __shared__ float tile[32][33];
    size_t mat = (size_t)blockIdx.z * R * S;
    int s0 = blockIdx.x * 32, r0 = blockIdx.y * 32;
    int tid = threadIdx.x;
    int rr = tid >> 3, sc = (tid & 7) * 4;
    float4 v = *(const float4*)(in + mat + (size_t)(r0 + rr) * S + s0 + sc);
    tile[rr][sc + 0] = v.x; tile[rr][sc + 1] = v.y;
    tile[rr][sc + 2] = v.z; tile[rr][sc + 3] = v.w;
    __syncthreads();
    int ss = tid >> 3, rc = (tid & 7) * 4;
    bf16 tmp[4];
    #pragma unroll
    for (int i = 0; i < 4; ++i) tmp[i] = __float2bfloat16(tile[rc + i][ss]);
    *(uint2*)(out + mat + (size_t)(s0 + ss) * R + r0 + rc) = *(uint2*)tmp;
}

// gate: fp32 logits, sigmoid, top-4, normalize, build expert lists + token-major slots
__global__ void k_gate(const float* __restrict__ x, const float* __restrict__ wg,
                       const float* __restrict__ bias, int* __restrict__ cnt,
                       int* __restrict__ tok, float* __restrict__ wl,
                       int* __restrict__ slotk) {
    __shared__ float gates[16][17];
    int t = threadIdx.x;
    int tl = t >> 4;
    int e = t & 15;
    int token = blockIdx.x * 16 + tl;
    const float* xr = x + (size_t)token * 768;
    float acc = 0.f;
    #pragma unroll 4
    for (int c = 0; c < 768; ++c) acc += xr[c] * wg[c * 16 + e];
    acc += bias[e];
    gates[tl][e] = 1.f / (1.f + expf(-acc));
    __syncthreads();
    if (t < 16) {
        int token2 = blockIdx.x * 16 + t;
        float g[16];
        #pragma unroll
        for (int j = 0; j < 16; ++j) g[j] = gates[t][j];
        int idx[4]; float w[4]; float sum = 0.f;
        #pragma unroll
        for (int k = 0; k < 4; ++k) {
            float best = -1e30f; int bi = 0;
            #pragma unroll
            for (int j = 0; j < 16; ++j)
                if (g[j] > best) { best = g[j]; bi = j; }
            idx[k] = bi; w[k] = best; sum += best; g[bi] = -1e30f;
        }
        float inv = 1.f / sum;
        for (int k = 0; k < 4; ++k) {
            int slot = atomicAdd(&cnt[idx[k]], 1);
            tok[(idx[k] << 13) + slot] = token2;
            wl[(idx[k] << 13) + slot] = w[k] * inv;
            slotk[token2 * 4 + k] = (idx[k] << 13) | slot;
        }
    }
}

__global__ void k_offsets(const int* __restrict__ cnt, int* __restrict__ offs) {
    if (threadIdx.x == 0) {
        int s = 0;
        for (int e = 0; e < 16; ++e) { offs[e] = s; s += cnt[e]; }
    }
}

// combine: out[t] += sum_k routed[offs[e_k] + slot_k]   (weights applied in proj)
__global__ __launch_bounds__(192) void k_combine(
    const float* __restrict__ routed, const int* __restrict__ slotk,
    const int* __restrict__ offs, float* __restrict__ out) {
    int t = blockIdx.x;
    int c4 = threadIdx.x * 4;
    float* op = out + (size_t)t * 768 + c4;
    float4 acc = *(float4*)op;
    #pragma unroll
    for (int k = 0; k < 4; ++k) {
        int sk = slotk[t * 4 + k];
        int e = sk >> 13, sl = sk & 8191;
        const float* row = routed + (size_t)(offs[e] + sl) * 768 + c4;
        float4 v = *(const float4*)row;
        acc.x += v.x; acc.y += v.y; acc.z += v.z; acc.w += v.w;
    }
    *(float4*)op = acc;
}

// ---------------- FC GEMM with fused SwiGLU ----------------
// A [*,768] bf16, BT [(E*)6144,768] bf16, act [*,3072] bf16.
// Tile 128 rows x 128 act cols; 512 threads = 8 waves; wm=w&1, wn=w>>1.
// LDS XOR swizzle: chunk (row r, k2) at slot r*4 + (k2 ^ ((r>>1)&3)).
template<int GATHER>
__global__ __launch_bounds__(512) void k_fc_swiglu(
    const bf16* __restrict__ A, const bf16* __restrict__ BT,
    bf16* __restrict__ act, const int* __restrict__ cnt,
    const int* __restrict__ offs, const int* __restrict__ tok) {
    const int Kd = 768, H = 3072;
    int e = blockIdx.z;
    int m0 = blockIdx.y * 128;
    int n0 = blockIdx.x * 128;
    int M;
    size_t actbase = 0;
    const int* tl = nullptr;
    if (GATHER) {
        M = cnt[e];
        if (m0 >= M) return;
        tl = tok + (e << 13);
        actbase = (size_t)offs[e] * H;
        BT += (size_t)e * 6144 * Kd;
    } else {
        M = 8192;
    }

    __shared__ bf16 sA[128 * BK];
    __shared__ bf16 sBg[128 * BK];
    __shared__ bf16 sBv[128 * BK];

    int tid = threadIdx.x;
    int lane = tid & 63;
    int w = tid >> 6;
    int wm = w & 1, wn = w >> 1;

    int sr = tid >> 2;
    int k2 = (tid & 3) ^ ((sr >> 1) & 3);

    int grA = GATHER ? tl[min(m0 + sr, M - 1)] : (m0 + sr);
    const bf16* gA  = A  + (size_t)grA * Kd + k2 * 8;
    const bf16* gBg = BT + (size_t)(n0 + sr) * Kd + k2 * 8;
    const bf16* gBv = BT + (size_t)(H + n0 + sr) * Kd + k2 * 8;
    bf16* sAp  = sA  + tid * 8;
    bf16* sBgp = sBg + tid * 8;
    bf16* sBvp = sBv + tid * 8;

    float4v ag[4][2] = {};
    float4v av[4][2] = {};
    int quad = lane >> 4, l16 = lane & 15;
    int q2 = quad ^ ((l16 >> 1) & 3);

    for (int k0 = 0; k0 < Kd; k0 += BK) {
        __syncthreads();
        gload16(gA + k0, sAp);
        gload16(gBg + k0, sBgp);
        gload16(gBv + k0, sBvp);
        __syncthreads();
        short8 af[4], bg[2], bv[2];
        #pragma unroll
        for (int mf = 0; mf < 4; ++mf) {
            int row = wm * 64 + mf * 16 + l16;
            af[mf] = *(const short8*)(sA + row * BK + q2 * 8);
        }
        #pragma unroll
        for (int nf = 0; nf < 2; ++nf) {
            int row = wn * 32 + nf * 16 + l16;
            bg[nf] = *(const short8*)(sBg + row * BK + q2 * 8);
            bv[nf] = *(const short8*)(sBv + row * BK + q2 * 8);
        }
        #pragma unroll
        for (int mf = 0; mf < 4; ++mf)
            #pragma unroll
            for (int nf = 0; nf < 2; ++nf) {
                ag[mf][nf] = __builtin_amdgcn_mfma_f32_16x16x32_bf16(af[mf], bg[nf], ag[mf][nf], 0, 0, 0);
                av[mf][nf] = __builtin_amdgcn_mfma_f32_16x16x32_bf16(af[mf], bv[nf], av[mf][nf], 0, 0, 0);
            }
    }

    #pragma unroll
    for (int mf = 0; mf < 4; ++mf)
        #pragma unroll
        for (int nf = 0; nf < 2; ++nf)
            #pragma unroll
            for (int r = 0; r < 4; ++r) {
                int mrow = m0 + wm * 64 + mf * 16 + quad * 4 + r;
                if (GATHER && mrow >= M) continue;
                int col = n0 + wn * 32 + nf * 16 + l16;
                float g = ag[mf][nf][r];
                float v = av[mf][nf][r];
                float sg = g / (1.f + __expf(-g));
                act[actbase + (size_t)mrow * H + col] = __float2bfloat16(sg * v);
            }
}

// ---------------- Proj GEMM ----------------
// A [*,3072] bf16, PT [(E*)768,3072] bf16.
// Dense: out [8192,768] fp32 plain stores. Routed: weighted rows ->
// routed_out[offs[e]+slot][768] plain stores (combined later).
// Tile 256x128, 512 threads = 8 waves; wm=w&3, wn=w>>2.
template<int ROUTED>
__global__ __launch_bounds__(512) void k_proj(
    const bf16* __restrict__ Aact, const bf16* __restrict__ PT,
    float* __restrict__ out, const int* __restrict__ cnt,
    const int* __restrict__ offs, const float* __restrict__ wl) {
    const int Kd = 3072;
    int e = blockIdx.z;
    int m0 = blockIdx.y * 256;
    int n0 = blockIdx.x * 128;
    int M;
    size_t abase = 0;
    int roffs = 0;
    if (ROUTED) {
        M = cnt[e];
        if (m0 >= M) return;
        roffs = offs[e];
        abase = (size_t)roffs * Kd;
        PT += (size_t)e * 768 * Kd;
    } else {
        M = 8192;
    }

    __shared__ bf16 sA[256 * BK];
    __shared__ bf16 sB[128 * BK];

    int tid = threadIdx.x, lane = tid & 63, w = tid >> 6;
    int wm = w & 3, wn = w >> 2;

    int srA0 = tid >> 2;
    int srA1 = (tid + 512) >> 2;
    int k2A0 = (tid & 3) ^ ((srA0 >> 1) & 3);
    int k2A1 = (tid & 3) ^ ((srA1 >> 1) & 3);
    int srB = tid >> 2;
    int k2B = (tid & 3) ^ ((srB >> 1) & 3);

    int ra0 = min(m0 + srA0, M - 1);
    int ra1 = min(m0 + srA1, M - 1);
    const bf16* gA0 = Aact + abase + (size_t)ra0 * Kd + k2A0 * 8;
    const bf16* gA1 = Aact + abase + (size_t)ra1 * Kd + k2A1 * 8;
    const bf16* gB  = PT + (size_t)(n0 + srB) * Kd + k2B * 8;
    bf16* sA0p = sA + tid * 8;
    bf16* sA1p = sA + (tid + 512) * 8;
    bf16* sBp  = sB + tid * 8;

    float4v acc[4][4] = {};
    int quad = lane >> 4, l16 = lane & 15;
    int q2 = quad ^ ((l16 >> 1) & 3);

    for (int kk = 0; kk < Kd; kk += BK) {
        __syncthreads();
        gload16(gA0 + kk, sA0p);
        gload16(gA1 + kk, sA1p);
        gload16(gB + kk, sBp);
        __syncthreads();
        short8 af[4], bb[4];
        #pragma unroll
        for (int i = 0; i < 4; ++i) {
            int rowa = wm * 64 + i * 16 + l16;
            int rowb = wn * 64 + i * 16 + l16;
            af[i] = *(const short8*)(sA + rowa * BK + q2 * 8);
            bb[i] = *(const short8*)(sB + rowb * BK + q2 * 8);
        }
        #pragma unroll
        for (int mf = 0; mf < 4; ++mf)
            #pragma unroll
            for (int nf = 0; nf < 4; ++nf)
                acc[mf][nf] = __builtin_amdgcn_mfma_f32_16x16x32_bf16(af[mf], bb[nf], acc[mf][nf], 0, 0, 0);
    }

    #pragma unroll
    for (int mf = 0; mf < 4; ++mf) {
        #pragma unroll
        for (int r = 0; r < 4; ++r) {
            int mr = m0 + wm * 64 + mf * 16 + quad * 4 + r;
            if (ROUTED) {
                if (mr < M) {
                    float wgt = wl[(e << 13) + mr];
                    float* orow = out + (size_t)(roffs + mr) * 768;
                    #pragma unroll
                    for (int nf = 0; nf < 4; ++nf) {
                        int col = n0 + wn * 64 + nf * 16 + l16;
                        orow[col] = wgt * acc[mf][nf][r];
                    }
                }
            } else {
                #pragma unroll
                for (int nf = 0; nf < 4; ++nf) {
                    int col = n0 + wn * 64 + nf * 16 + l16;
                    out[(size_t)mr * 768 + col] = acc[mf][nf][r];
                }
            }
        }
    }
}

// ---------------- launch ----------------

extern "C" void kernel_launch(void* const* d_in, const int* in_sizes, int n_in,
                              void* d_out, int out_size, void* d_ws, size_t ws_size,
                              hipStream_t stream) {
    const float* x    = (const float*)d_in[0];
    const float* wfc  = (const float*)d_in[1];
    const float* wpr  = (const float*)d_in[2];
    const float* wefc = (const float*)d_in[3];
    const float* wepr = (const float*)d_in[4];
    const float* wg   = (const float*)d_in[5];
    const float* eb   = (const float*)d_in[6];
    float* out = (float*)d_out;

    char* p = (char*)d_ws;
    bf16* x_bf  = (bf16*)p; p += (size_t)8192 * 768 * 2;
    bf16* fcT_s = (bf16*)p; p += (size_t)6144 * 768 * 2;
    bf16* prT_s = (bf16*)p; p += (size_t)768 * 3072 * 2;
    bf16* fcT_e = (bf16*)p; p += (size_t)16 * 6144 * 768 * 2;   // dead after fc<1>
    bf16* prT_e = (bf16*)p; p += (size_t)16 * 768 * 3072 * 2;
    bf16* act_s = (bf16*)p; p += (size_t)8192 * 3072 * 2;
    bf16* act_r = (bf16*)p; p += (size_t)32768 * 3072 * 2;
    int* cnt    = (int*)p;  p += 64;
    int* offs   = (int*)p;  p += 64;
    int* tok    = (int*)p;  p += (size_t)16 * 8192 * 4;
    float* wl   = (float*)p; p += (size_t)16 * 8192 * 4;
    int* slotk  = (int*)p;  p += (size_t)8192 * 4 * 4;
    // routed_out aliases fcT_e (151 MB >= 100.7 MB needed; fc<1> done before proj<1>)
    float* routed_out = (float*)fcT_e;

    k_convert_x<<<dim3(6144), dim3(256), 0, stream>>>(x, x_bf, 8192 * 768, cnt);
    k_transpose<<<dim3(192, 24, 1), dim3(256), 0, stream>>>(wfc, fcT_s, 768, 6144);
    k_transpose<<<dim3(24, 96, 1), dim3(256), 0, stream>>>(wpr, prT_s, 3072, 768);
    k_transpose<<<dim3(192, 24, 16), dim3(256), 0, stream>>>(wefc, fcT_e, 768, 6144);
    k_transpose<<<dim3(24, 96, 16), dim3(256), 0, stream>>>(wepr, prT_e, 3072, 768);
    k_gate<<<dim3(512), dim3(256), 0, stream>>>(x, wg, eb, cnt, tok, wl, slotk);
    k_offsets<<<dim3(1), dim3(64), 0, stream>>>(cnt, offs);

    k_fc_swiglu<0><<<dim3(24, 64, 1), dim3(512), 0, stream>>>(x_bf, fcT_s, act_s, cnt, offs, tok);
    k_fc_swiglu<1><<<dim3(24, 64, 16), dim3(512), 0, stream>>>(x_bf, fcT_e, act_r, cnt, offs, tok);
    k_proj<0><<<dim3(6, 32, 1), dim3(512), 0, stream>>>(act_s, prT_s, out, cnt, offs, wl);
    k_proj<1><<<dim3(6, 32, 16), dim3(512), 0, stream>>>(act_r, prT_e, routed_out, cnt, offs, wl);
    k_combine<<<dim3(8192), dim3(192), 0, stream>>>(routed_out, slotk, offs, out);
}

// Round 4
// 1639.059 us; speedup vs baseline: 1.0077x; 1.0077x over previous
//
#include <hip/hip_runtime.h>
#include <hip/hip_bf16.h>

typedef __hip_bfloat16 bf16;
typedef __attribute__((ext_vector_type(8))) short short8;
typedef __attribute__((ext_vector_type(4))) float float4v;

#define BK 32

__device__ __forceinline__ void gload16(const bf16* g, bf16* s) {
    __builtin_amdgcn_global_load_lds(
        (const __attribute__((address_space(1))) void*)g,
        (__attribute__((address_space(3))) void*)s, 16, 0, 0);
}

// ---------------- small utility kernels ----------------

__global__ void k_convert_x(const float* __restrict__ in, bf16* __restrict__ out,
                            int n, int* __restrict__ cnt) {
    if (blockIdx.x == 0 && threadIdx.x < 16) cnt[threadIdx.x] = 0;
    int i = (blockIdx.x * blockDim.x + threadIdx.x) * 4;
    if (i + 3 < n) {
        float4 v = *(const float4*)(in + i);
        out[i + 0] = __float2bfloat16(v.x);
        out[i + 1] = __float2bfloat16(v.y);
        out[i + 2] = __float2bfloat16(v.z);
        out[i + 3] = __float2bfloat16(v.w);
    }
}

// in: [R,S] fp32 -> out: [S,R] bf16 (batched over z). 64x64 tile, 256 threads.
// Reads float4/lane, writes 16B (8 bf16)/lane. LDS [64][65]: write-phase bank
// = (8*(l&7) + (l>>3) + j) mod 32 -> every bank hit exactly 2x = free (m136).
__global__ __launch_bounds__(256) void k_transpose64(
    const float* __restrict__ in, bf16* __restrict__ out, int R, int S) {
    __shared__ float tile[64][65];
    size_t mat = (size_t)blockIdx.z * R * S;
    int s0 = blockIdx.x * 64, r0 = blockIdx.y * 64;
    int tid = threadIdx.x;
    int rr = tid >> 4, sc = (tid & 15) * 4;
    #pragma unroll
    for (int i = 0; i < 4; ++i) {
        float4 v = *(const float4*)(in + mat + (size_t)(r0 + rr + i * 16) * S + s0 + sc);
        tile[rr + i * 16][sc + 0] = v.x;
        tile[rr + i * 16][sc + 1] = v.y;
        tile[rr + i * 16][sc + 2] = v.z;
        tile[rr + i * 16][sc + 3] = v.w;
    }
    __syncthreads();
    int ss = tid >> 3, rc = (tid & 7) * 8;
    #pragma unroll
    for (int i = 0; i < 2; ++i) {
        int s = ss + i * 32;
        bf16 tmp[8];
        #pragma unroll
        for (int j = 0; j < 8; ++j) tmp[j] = __float2bfloat16(tile[rc + j][s]);
        *(uint4*)(out + mat + (size_t)(s0 + s) * R + r0 + rc) = *(uint4*)tmp;
    }
}

// gate: fp32 logits, sigmoid, top-4, normalize, build expert lists + token-major slots
__global__ void k_gate(const float* __restrict__ x, const float* __restrict__ wg,
                       const float* __restrict__ bias, int* __restrict__ cnt,
                       int* __restrict__ tok, float* __restrict__ wl,
                       int* __restrict__ slotk) {
    __shared__ float gates[16][17];
    int t = threadIdx.x;
    int tl = t >> 4;
    int e = t & 15;
    int token = blockIdx.x * 16 + tl;
    const float* xr = x + (size_t)token * 768;
    float acc = 0.f;
    #pragma unroll 4
    for (int c = 0; c < 768; ++c) acc += xr[c] * wg[c * 16 + e];
    acc += bias[e];
    gates[tl][e] = 1.f / (1.f + expf(-acc));
    __syncthreads();
    if (t < 16) {
        int token2 = blockIdx.x * 16 + t;
        float g[16];
        #pragma unroll
        for (int j = 0; j < 16; ++j) g[j] = gates[t][j];
        int idx[4]; float w[4]; float sum = 0.f;
        #pragma unroll
        for (int k = 0; k < 4; ++k) {
            float best = -1e30f; int bi = 0;
            #pragma unroll
            for (int j = 0; j < 16; ++j)
                if (g[j] > best) { best = g[j]; bi = j; }
            idx[k] = bi; w[k] = best; sum += best; g[bi] = -1e30f;
        }
        float inv = 1.f / sum;
        for (int k = 0; k < 4; ++k) {
            int slot = atomicAdd(&cnt[idx[k]], 1);
            tok[(idx[k] << 13) + slot] = token2;
            wl[(idx[k] << 13) + slot] = w[k] * inv;
            slotk[token2 * 4 + k] = (idx[k] << 13) | slot;
        }
    }
}

__global__ void k_offsets(const int* __restrict__ cnt, int* __restrict__ offs) {
    if (threadIdx.x == 0) {
        int s = 0;
        for (int e = 0; e < 16; ++e) { offs[e] = s; s += cnt[e]; }
    }
}

// combine: out[t] += sum_k routed[offs[e_k] + slot_k]   (weights applied in proj)
__global__ __launch_bounds__(192) void k_combine(
    const float* __restrict__ routed, const int* __restrict__ slotk,
    const int* __restrict__ offs, float* __restrict__ out) {
    int t = blockIdx.x;
    int c4 = threadIdx.x * 4;
    float* op = out + (size_t)t * 768 + c4;
    float4 acc = *(float4*)op;
    #pragma unroll
    for (int k = 0; k < 4; ++k) {
        int sk = slotk[t * 4 + k];
        int e = sk >> 13, sl = sk & 8191;
        const float* row = routed + (size_t)(offs[e] + sl) * 768 + c4;
        float4 v = *(const float4*)row;
        acc.x += v.x; acc.y += v.y; acc.z += v.z; acc.w += v.w;
    }
    *(float4*)op = acc;
}

// ---------------- FC GEMM with fused SwiGLU ----------------
template<int GATHER>
__device__ __forceinline__ void fc_body(
    const bf16* __restrict__ A, const bf16* __restrict__ BT,
    bf16* __restrict__ act, const int* __restrict__ cnt,
    const int* __restrict__ offs, const int* __restrict__ tok) {
    const int Kd = 768, H = 3072;
    int e = blockIdx.z;
    int m0 = blockIdx.y * 128;
    int n0 = blockIdx.x * 128;
    int M;
    size_t actbase = 0;
    const int* tl = nullptr;
    if (GATHER) {
        M = cnt[e];
        if (m0 >= M) return;
        tl = tok + (e << 13);
        actbase = (size_t)offs[e] * H;
        BT += (size_t)e * 6144 * Kd;
    } else {
        M = 8192;
    }

    __shared__ bf16 sA[128 * BK];
    __shared__ bf16 sBg[128 * BK];
    __shared__ bf16 sBv[128 * BK];

    int tid = threadIdx.x;
    int lane = tid & 63;
    int w = tid >> 6;
    int wm = w & 1, wn = w >> 1;

    int sr = tid >> 2;
    int k2 = (tid & 3) ^ ((sr >> 1) & 3);

    int grA = GATHER ? tl[min(m0 + sr, M - 1)] : (m0 + sr);
    const bf16* gA  = A  + (size_t)grA * Kd + k2 * 8;
    const bf16* gBg = BT + (size_t)(n0 + sr) * Kd + k2 * 8;
    const bf16* gBv = BT + (size_t)(H + n0 + sr) * Kd + k2 * 8;
    bf16* sAp  = sA  + tid * 8;
    bf16* sBgp = sBg + tid * 8;
    bf16* sBvp = sBv + tid * 8;

    float4v ag[4][2] = {};
    float4v av[4][2] = {};
    int quad = lane >> 4, l16 = lane & 15;
    int q2 = quad ^ ((l16 >> 1) & 3);

    for (int k0 = 0; k0 < Kd; k0 += BK) {
        __syncthreads();
        gload16(gA + k0, sAp);
        gload16(gBg + k0, sBgp);
        gload16(gBv + k0, sBvp);
        __syncthreads();
        short8 af[4], bg[2], bv[2];
        #pragma unroll
        for (int mf = 0; mf < 4; ++mf) {
            int row = wm * 64 + mf * 16 + l16;
            af[mf] = *(const short8*)(sA + row * BK + q2 * 8);
        }
        #pragma unroll
        for (int nf = 0; nf < 2; ++nf) {
            int row = wn * 32 + nf * 16 + l16;
            bg[nf] = *(const short8*)(sBg + row * BK + q2 * 8);
            bv[nf] = *(const short8*)(sBv + row * BK + q2 * 8);
        }
        #pragma unroll
        for (int mf = 0; mf < 4; ++mf)
            #pragma unroll
            for (int nf = 0; nf < 2; ++nf) {
                ag[mf][nf] = __builtin_amdgcn_mfma_f32_16x16x32_bf16(af[mf], bg[nf], ag[mf][nf], 0, 0, 0);
                av[mf][nf] = __builtin_amdgcn_mfma_f32_16x16x32_bf16(af[mf], bv[nf], av[mf][nf], 0, 0, 0);
            }
    }

    #pragma unroll
    for (int mf = 0; mf < 4; ++mf)
        #pragma unroll
        for (int nf = 0; nf < 2; ++nf)
            #pragma unroll
            for (int r = 0; r < 4; ++r) {
                int mrow = m0 + wm * 64 + mf * 16 + quad * 4 + r;
                if (GATHER && mrow >= M) continue;
                int col = n0 + wn * 32 + nf * 16 + l16;
                float g = ag[mf][nf][r];
                float v = av[mf][nf][r];
                float sg = g / (1.f + __expf(-g));
                act[actbase + (size_t)mrow * H + col] = __float2bfloat16(sg * v);
            }
}

__global__ __launch_bounds__(512) void k_fc_shared(
    const bf16* __restrict__ A, const bf16* __restrict__ BT, bf16* __restrict__ act,
    const int* __restrict__ cnt, const int* __restrict__ offs, const int* __restrict__ tok) {
    fc_body<0>(A, BT, act, cnt, offs, tok);
}
__global__ __launch_bounds__(512) void k_fc_routed(
    const bf16* __restrict__ A, const bf16* __restrict__ BT, bf16* __restrict__ act,
    const int* __restrict__ cnt, const int* __restrict__ offs, const int* __restrict__ tok) {
    fc_body<1>(A, BT, act, cnt, offs, tok);
}

// ---------------- Proj GEMM ----------------
template<int ROUTED>
__device__ __forceinline__ void proj_body(
    const bf16* __restrict__ Aact, const bf16* __restrict__ PT,
    float* __restrict__ out, const int* __restrict__ cnt,
    const int* __restrict__ offs, const float* __restrict__ wl) {
    const int Kd = 3072;
    int e = blockIdx.z;
    int m0 = blockIdx.y * 256;
    int n0 = blockIdx.x * 128;
    int M;
    size_t abase = 0;
    int roffs = 0;
    if (ROUTED) {
        M = cnt[e];
        if (m0 >= M) return;
        roffs = offs[e];
        abase = (size_t)roffs * Kd;
        PT += (size_t)e * 768 * Kd;
    } else {
        M = 8192;
    }

    __shared__ bf16 sA[256 * BK];
    __shared__ bf16 sB[128 * BK];

    int tid = threadIdx.x, lane = tid & 63, w = tid >> 6;
    int wm = w & 3, wn = w >> 2;

    int srA0 = tid >> 2;
    int srA1 = (tid + 512) >> 2;
    int k2A0 = (tid & 3) ^ ((srA0 >> 1) & 3);
    int k2A1 = (tid & 3) ^ ((srA1 >> 1) & 3);
    int srB = tid >> 2;
    int k2B = (tid & 3) ^ ((srB >> 1) & 3);

    int ra0 = min(m0 + srA0, M - 1);
    int ra1 = min(m0 + srA1, M - 1);
    const bf16* gA0 = Aact + abase + (size_t)ra0 * Kd + k2A0 * 8;
    const bf16* gA1 = Aact + abase + (size_t)ra1 * Kd + k2A1 * 8;
    const bf16* gB  = PT + (size_t)(n0 + srB) * Kd + k2B * 8;
    bf16* sA0p = sA + tid * 8;
    bf16* sA1p = sA + (tid + 512) * 8;
    bf16* sBp  = sB + tid * 8;

    float4v acc[4][4] = {};
    int quad = lane >> 4, l16 = lane & 15;
    int q2 = quad ^ ((l16 >> 1) & 3);

    for (int kk = 0; kk < Kd; kk += BK) {
        __syncthreads();
        gload16(gA0 + kk, sA0p);
        gload16(gA1 + kk, sA1p);
        gload16(gB + kk, sBp);
        __syncthreads();
        short8 af[4], bb[4];
        #pragma unroll
        for (int i = 0; i < 4; ++i) {
            int rowa = wm * 64 + i * 16 + l16;
            int rowb = wn * 64 + i * 16 + l16;
            af[i] = *(const short8*)(sA + rowa * BK + q2 * 8);
            bb[i] = *(const short8*)(sB + rowb * BK + q2 * 8);
        }
        #pragma unroll
        for (int mf = 0; mf < 4; ++mf)
            #pragma unroll
            for (int nf = 0; nf < 4; ++nf)
                acc[mf][nf] = __builtin_amdgcn_mfma_f32_16x16x32_bf16(af[mf], bb[nf], acc[mf][nf], 0, 0, 0);
    }

    #pragma unroll
    for (int mf = 0; mf < 4; ++mf) {
        #pragma unroll
        for (int r = 0; r < 4; ++r) {
            int mr = m0 + wm * 64 + mf * 16 + quad * 4 + r;
            if (ROUTED) {
                if (mr < M) {
                    float wgt = wl[(e << 13) + mr];
                    float* orow = out + (size_t)(roffs + mr) * 768;
                    #pragma unroll
                    for (int nf = 0; nf < 4; ++nf) {
                        int col = n0 + wn * 64 + nf * 16 + l16;
                        orow[col] = wgt * acc[mf][nf][r];
                    }
                }
            } else {
                #pragma unroll
                for (int nf = 0; nf < 4; ++nf) {
                    int col = n0 + wn * 64 + nf * 16 + l16;
                    out[(size_t)mr * 768 + col] = acc[mf][nf][r];
                }
            }
        }
    }
}

__global__ __launch_bounds__(512) void k_proj_shared(
    const bf16* __restrict__ Aact, const bf16* __restrict__ PT, float* __restrict__ out,
    const int* __restrict__ cnt, const int* __restrict__ offs, const float* __restrict__ wl) {
    proj_body<0>(Aact, PT, out, cnt, offs, wl);
}
__global__ __launch_bounds__(512) void k_proj_routed(
    const bf16* __restrict__ Aact, const bf16* __restrict__ PT, float* __restrict__ out,
    const int* __restrict__ cnt, const int* __restrict__ offs, const float* __restrict__ wl) {
    proj_body<1>(Aact, PT, out, cnt, offs, wl);
}

// ---------------- launch ----------------

extern "C" void kernel_launch(void* const* d_in, const int* in_sizes, int n_in,
                              void* d_out, int out_size, void* d_ws, size_t ws_size,
                              hipStream_t stream) {
    const float* x    = (const float*)d_in[0];
    const float* wfc  = (const float*)d_in[1];
    const float* wpr  = (const float*)d_in[2];
    const float* wefc = (const float*)d_in[3];
    const float* wepr = (const float*)d_in[4];
    const float* wg   = (const float*)d_in[5];
    const float* eb   = (const float*)d_in[6];
    float* out = (float*)d_out;

    char* p = (char*)d_ws;
    bf16* x_bf  = (bf16*)p; p += (size_t)8192 * 768 * 2;
    bf16* fcT_s = (bf16*)p; p += (size_t)6144 * 768 * 2;
    bf16* prT_s = (bf16*)p; p += (size_t)768 * 3072 * 2;
    bf16* fcT_e = (bf16*)p; p += (size_t)16 * 6144 * 768 * 2;   // dead after fc_routed
    bf16* prT_e = (bf16*)p; p += (size_t)16 * 768 * 3072 * 2;
    bf16* act_s = (bf16*)p; p += (size_t)8192 * 3072 * 2;
    bf16* act_r = (bf16*)p; p += (size_t)32768 * 3072 * 2;
    int* cnt    = (int*)p;  p += 64;
    int* offs   = (int*)p;  p += 64;
    int* tok    = (int*)p;  p += (size_t)16 * 8192 * 4;
    float* wl   = (float*)p; p += (size_t)16 * 8192 * 4;
    int* slotk  = (int*)p;  p += (size_t)8192 * 4 * 4;
    float* routed_out = (float*)fcT_e;  // aliases fcT_e (151 MB >= 100.7 MB)

    k_convert_x<<<dim3(6144), dim3(256), 0, stream>>>(x, x_bf, 8192 * 768, cnt);
    k_transpose64<<<dim3(96, 12, 1), dim3(256), 0, stream>>>(wfc, fcT_s, 768, 6144);
    k_transpose64<<<dim3(12, 48, 1), dim3(256), 0, stream>>>(wpr, prT_s, 3072, 768);
    k_transpose64<<<dim3(96, 12, 16), dim3(256), 0, stream>>>(wefc, fcT_e, 768, 6144);
    k_transpose64<<<dim3(12, 48, 16), dim3(256), 0, stream>>>(wepr, prT_e, 3072, 768);
    k_gate<<<dim3(512), dim3(256), 0, stream>>>(x, wg, eb, cnt, tok, wl, slotk);
    k_offsets<<<dim3(1), dim3(64), 0, stream>>>(cnt, offs);

    k_fc_shared<<<dim3(24, 64, 1), dim3(512), 0, stream>>>(x_bf, fcT_s, act_s, cnt, offs, tok);
    k_fc_routed<<<dim3(24, 64, 16), dim3(512), 0, stream>>>(x_bf, fcT_e, act_r, cnt, offs, tok);
    k_proj_shared<<<dim3(6, 32, 1), dim3(512), 0, stream>>>(act_s, prT_s, out, cnt, offs, wl);
    k_proj_routed<<<dim3(6, 32, 16), dim3(512), 0, stream>>>(act_r, prT_e, routed_out, cnt, offs, wl);
    k_combine<<<dim3(8192), dim3(192), 0, stream>>>(routed_out, slotk, offs, out);
}